// Round 11
// baseline (513.594 us; speedup 1.0000x reference)
//
#include <hip/hip_runtime.h>
#include <hip/hip_bf16.h>

#define B_  64
#define S_  128
#define WP_ 18
#define K_  3
#define E_  128
#define H_  256
#define L_  4
#define T_  50

typedef __hip_bfloat16 bf16;

__device__ __forceinline__ float b2f(bf16 x) { return __bfloat162float(x); }
__device__ __forceinline__ bf16  f2b(float x) { return __float2bfloat16(x); }

__device__ __forceinline__ float fast_sigmoid(float x) {
    return 1.f / (1.f + __expf(-x));
}
__device__ __forceinline__ float fast_tanh(float x) {
    float a = fminf(fmaxf(2.f * x, -30.f), 30.f);
    float e = __expf(a);
    return (e - 1.f) / (e + 1.f);
}

// v_dot2_f32_bf16: z += lo(w)*lo(h) + hi(w)*hi(h), all ops one VALU inst
#define DOT2(z, w, h) asm("v_dot2_f32_bf16 %0, %1, %2, %0" : "+v"(z) : "v"(w), "v"(h))

// ---------------------------------------------------------------- transpose (f32 -> bf16)
__global__ void k_transpose(const float* __restrict__ src, bf16* __restrict__ dst,
                            int R, int C) {
    int i = blockIdx.x * 256 + threadIdx.x;
    if (i >= R * C) return;
    int r = i / C, c = i % C;
    dst[c * R + r] = f2b(src[i]);
}

// ---------------------------------------------------------------- pack Whh for k-split layout
// thread (i,p) [t=i*4+p] needs w[col=g*256+i][k=64p..64p+63] as 8 uint4 (m=g*8+kk).
// dst uint4 index = m*1024 + t; bf16 element e = k&7.
__global__ void k_pack_whh(const float* __restrict__ src, bf16* __restrict__ dst) {
    int idx = blockIdx.x * 256 + threadIdx.x;   // over 1024*256
    if (idx >= 1024 * 256) return;
    int col = idx >> 8, k = idx & 255;
    int g = col >> 8, i = col & 255;
    int p = k >> 6, kk = (k >> 3) & 7, e = k & 7;
    int t = i * 4 + p, m = g * 8 + kk;
    dst[((size_t)(m * 1024 + t) << 3) + e] = f2b(src[col * 256 + k]);
}

// ---------------------------------------------------------------- char CNN
__global__ void k_charcnn(const int* __restrict__ char_ids,
                          const float* __restrict__ char_emb,
                          const float* __restrict__ cnn_w,
                          const float* __restrict__ cnn_b,
                          float* __restrict__ out_char) {
    const int CE_S = 132;
    const int W_S  = 388;
    __shared__ float ce[WP_ * 132];
    __shared__ float w[L_ * 388];
    __shared__ float bias[L_];
    int idx = blockIdx.x;            // b*S + s
    int t   = threadIdx.x;           // 0..63
    const int* ids = char_ids + idx * WP_;
    for (int i = t; i < WP_ * E_; i += 64) {
        int r = i >> 7, e = i & 127;
        ce[r * CE_S + e] = char_emb[ids[r] * E_ + e];
    }
    for (int i = t; i < L_ * K_ * E_; i += 64) {
        int r = i / (K_ * E_), e = i % (K_ * E_);
        w[r * W_S + e] = cnn_w[i];
    }
    if (t < L_) bias[t] = cnn_b[t];
    __syncthreads();
    int pos = t >> 2, c = t & 3;     // 16 positions x 4 channels
    float acc = 0.f;
    const float* wr = &w[c * W_S];
    #pragma unroll
    for (int i = 0; i < K_; ++i) {
        const float* cr = &ce[(pos + i) * CE_S];
        #pragma unroll 8
        for (int e = 0; e < E_; ++e) acc = fmaf(cr[e], wr[i * E_ + e], acc);
    }
    acc += bias[c];
    #pragma unroll
    for (int off = 4; off < 64; off <<= 1) acc = fmaxf(acc, __shfl_xor(acc, off));
    if (t < L_) out_char[idx * L_ + t] = acc;
}

// ---------------------------------------------------------------- input proj
// igq[row*1024 + i*4 + g] = b[g*256+i] + sum_k we[row,k]*WihT[k, g*256+i]
__global__ void k_input_proj(const int* __restrict__ word_ids,
                             const float* __restrict__ word_emb,
                             const bf16* __restrict__ wihT_f, const float* __restrict__ b_f,
                             const bf16* __restrict__ wihT_b, const float* __restrict__ b_b,
                             bf16* __restrict__ igq_f, bf16* __restrict__ igq_b) {
    int dir = blockIdx.y;
    const bf16* wihT = dir ? wihT_b : wihT_f;
    const float* bb  = dir ? b_b    : b_f;
    bf16* igq        = dir ? igq_b  : igq_f;
    __shared__ float x[8][128];
    int t  = threadIdx.x;            // 0..255 = unit i
    int r0 = blockIdx.x * 8;         // 8 rows (s*B+b) per block
    for (int i = t; i < 8 * 128; i += 256) {
        int rr = i >> 7, e = i & 127;
        int r = r0 + rr;
        int s = r >> 6, b = r & 63;
        int wid = word_ids[b * S_ + s];
        x[rr][e] = word_emb[(size_t)wid * E_ + e];
    }
    __syncthreads();
    int j = t;
    float acc[4][8];
    #pragma unroll
    for (int cj = 0; cj < 4; ++cj) {
        float bv = bb[j + cj * 256];
        #pragma unroll
        for (int rr = 0; rr < 8; ++rr) acc[cj][rr] = bv;
    }
    for (int k = 0; k < 128; ++k) {
        float wv[4];
        #pragma unroll
        for (int cj = 0; cj < 4; ++cj) wv[cj] = b2f(wihT[k * 1024 + j + cj * 256]);
        #pragma unroll
        for (int rr = 0; rr < 8; ++rr) {
            float xv = x[rr][k];
            #pragma unroll
            for (int cj = 0; cj < 4; ++cj) acc[cj][rr] = fmaf(xv, wv[cj], acc[cj][rr]);
        }
    }
    #pragma unroll
    for (int cj = 0; cj < 4; ++cj)
        #pragma unroll
        for (int rr = 0; rr < 8; ++rr)
            igq[(size_t)(r0 + rr) * 1024 + j * 4 + cj] = f2b(acc[cj][rr]);
}

// ---------------------------------------------------------------- recurrence (k-split + dot2)
// One block per (batch, direction). Thread t: unit i=t>>2, k-slice p=t&3.
// Rebalanced three-tier weights: m=0..15 in registers (64 VGPR persistent),
// m=16..22 in LDS (112 KB), m=23..31 streamed from L2 (144 KB/step), all 9
// stream loads issued upfront for MLP.
__global__ __launch_bounds__(1024) void k_lstm_rec(
        const bf16* __restrict__ igq_f, const bf16* __restrict__ igq_b,
        const uint4* __restrict__ wp_f, const uint4* __restrict__ wp_b,
        float* __restrict__ hf, float* __restrict__ hb) {
    __shared__ uint4 wlds[7168];                    // 112 KiB, m = 16..22
    __shared__ __align__(16) unsigned int hpbuf[2][160];  // padded bf16-pair h, dbuf

    int b   = blockIdx.x & 63;
    int dir = blockIdx.x >> 6;
    const bf16* igq = dir ? igq_b : igq_f;
    const uint4* wp = dir ? wp_b  : wp_f;
    float* hs       = dir ? hb    : hf;

    int t = threadIdx.x;
    int i = t >> 2, p = t & 3;

    for (int u = t; u < 7168; u += 1024) wlds[u] = wp[16 * 1024 + u];
    if (t < 320) ((unsigned int*)hpbuf)[t] = 0;
    float c_reg = 0.f;

    // register tier: m = 0..15 (persistent, compile-time indexed after unroll)
    uint4 wreg[16];
    #pragma unroll
    for (int m = 0; m < 16; ++m) wreg[m] = wp[m * 1024 + t];
    __syncthreads();

    int cur = 0;
    int s0 = dir ? (S_ - 1) : 0;
    uint2 igu = *(const uint2*)&igq[((size_t)s0 * B_ + b) * 1024 + i * 4];

    for (int step = 0; step < S_; ++step) {
        int s = dir ? (S_ - 1 - step) : step;

        // issue ALL 9 streamed weight loads upfront (m=23, m=24..31)
        uint4 w23 = wp[23 * 1024 + t];
        uint4 gb[8];
        #pragma unroll
        for (int u = 0; u < 8; ++u) gb[u] = wp[(24 + u) * 1024 + t];

        float z0 = 0.f, z1 = 0.f, z2 = 0.f, z3 = 0.f;
        if (p == 0) {                       // seed ig term exactly once
            z0 = __uint_as_float(igu.x << 16);
            z1 = __uint_as_float(igu.x & 0xffff0000u);
            z2 = __uint_as_float(igu.y << 16);
            z3 = __uint_as_float(igu.y & 0xffff0000u);
        }
        const char* hpc = (const char*)hpbuf[cur];
        #pragma unroll
        for (int kk = 0; kk < 8; ++kk) {
            uint4 hv = *(const uint4*)(hpc + p * 144 + kk * 16);
            {   // g = 0, m = kk  -> registers
                uint4 wv = wreg[kk];
                DOT2(z0, wv.x, hv.x); DOT2(z0, wv.y, hv.y);
                DOT2(z0, wv.z, hv.z); DOT2(z0, wv.w, hv.w);
            }
            {   // g = 1, m = 8+kk -> registers
                uint4 wv = wreg[8 + kk];
                DOT2(z1, wv.x, hv.x); DOT2(z1, wv.y, hv.y);
                DOT2(z1, wv.z, hv.z); DOT2(z1, wv.w, hv.w);
            }
            {   // g = 2, m = 16+kk -> kk<7: LDS (m=16..22); kk==7: streamed m=23
                uint4 wv = (kk < 7) ? wlds[kk * 1024 + t] : w23;
                DOT2(z2, wv.x, hv.x); DOT2(z2, wv.y, hv.y);
                DOT2(z2, wv.z, hv.z); DOT2(z2, wv.w, hv.w);
            }
            {   // g = 3, m = 24+kk -> streamed
                uint4 wv = gb[kk];
                DOT2(z3, wv.x, hv.x); DOT2(z3, wv.y, hv.y);
                DOT2(z3, wv.z, hv.z); DOT2(z3, wv.w, hv.w);
            }
        }
        // prefetch next step's ig quad (hides L2 latency under reduce/gates)
        if (step + 1 < S_) {
            int sn = dir ? (S_ - 2 - step) : (step + 1);
            igu = *(const uint2*)&igq[((size_t)sn * B_ + b) * 1024 + i * 4];
        }
        // butterfly sum across p (lanes differing in bits 0-1)
        z0 += __shfl_xor(z0, 1); z0 += __shfl_xor(z0, 2);
        z1 += __shfl_xor(z1, 1); z1 += __shfl_xor(z1, 2);
        z2 += __shfl_xor(z2, 1); z2 += __shfl_xor(z2, 2);
        z3 += __shfl_xor(z3, 1); z3 += __shfl_xor(z3, 2);
        if (p == 0) {
            float si = fast_sigmoid(z0);
            float sf = fast_sigmoid(z1);
            float tg = fast_tanh(z2);
            float so = fast_sigmoid(z3);
            c_reg = sf * c_reg + si * tg;
            float hn = so * fast_tanh(c_reg);
            hs[((size_t)s * B_ + b) * 256 + i] = hn;
            // store bf16 h into next buffer: seg (i>>6), pair (i>>1)&31, half (i&1)
            char* dstb = (char*)hpbuf[cur ^ 1] + (i >> 6) * 144 + ((i >> 1) & 31) * 4 + (i & 1) * 2;
            *(bf16*)dstb = f2b(hn);
        }
        __syncthreads();
        cur ^= 1;
    }
}

// ---------------------------------------------------------------- tag linear
__global__ void k_tag_linear(const float* __restrict__ hf, const float* __restrict__ hb,
                             const float* __restrict__ out_w, const float* __restrict__ out_b,
                             float* __restrict__ tag) {
    int bs = blockIdx.x;             // b*S + s
    int b = bs >> 7, s = bs & 127;
    __shared__ float hv[512];
    int t = threadIdx.x;             // 0..63
    const float* hfr = hf + ((size_t)s * B_ + b) * 256;
    const float* hbr = hb + ((size_t)s * B_ + b) * 256;
    for (int i = t; i < 256; i += 64) { hv[i] = hfr[i]; hv[256 + i] = hbr[i]; }
    __syncthreads();
    if (t < T_) {
        float acc = out_b[t];
        #pragma unroll 8
        for (int k = 0; k < 512; ++k) acc = fmaf(hv[k], out_w[t * 512 + k], acc);
        tag[((size_t)b * T_ + t) * S_ + s] = acc;
    }
}

// ---------------------------------------------------------------- log_softmax over S (axis=1)
__global__ void k_log_softmax(const float* __restrict__ tag, float* __restrict__ out) {
    int wid  = (blockIdx.x * 256 + threadIdx.x) >> 6;   // one wave per (b,t)
    int lane = threadIdx.x & 63;
    if (wid >= B_ * T_) return;
    int b = wid / T_, t = wid % T_;
    const float* row = tag + (size_t)wid * S_;
    float v0 = row[lane], v1 = row[lane + 64];
    float m = fmaxf(v0, v1);
    #pragma unroll
    for (int off = 32; off; off >>= 1) m = fmaxf(m, __shfl_xor(m, off));
    float e = expf(v0 - m) + expf(v1 - m);
    #pragma unroll
    for (int off = 32; off; off >>= 1) e += __shfl_xor(e, off);
    float lse = m + logf(e);
    out[((size_t)b * S_ + lane)      * T_ + t] = v0 - lse;
    out[((size_t)b * S_ + lane + 64) * T_ + t] = v1 - lse;
}

// ---------------------------------------------------------------- launch
extern "C" void kernel_launch(void* const* d_in, const int* in_sizes, int n_in,
                              void* d_out, int out_size, void* d_ws, size_t ws_size,
                              hipStream_t stream) {
    const int*   char_ids = (const int*)d_in[0];
    const int*   word_ids = (const int*)d_in[1];
    const float* char_emb = (const float*)d_in[2];
    const float* word_emb = (const float*)d_in[3];
    const float* cnn_w    = (const float*)d_in[4];
    const float* cnn_b    = (const float*)d_in[5];
    const float* wih_f    = (const float*)d_in[6];
    const float* whh_f    = (const float*)d_in[7];
    const float* b_f      = (const float*)d_in[8];
    const float* wih_b    = (const float*)d_in[9];
    const float* whh_b    = (const float*)d_in[10];
    const float* b_b      = (const float*)d_in[11];
    const float* out_w    = (const float*)d_in[12];
    const float* out_b    = (const float*)d_in[13];
    float* out = (float*)d_out;
    char* ws   = (char*)d_ws;

    size_t o = 0;
    bf16* wihT_f = (bf16*)(ws + o); o += (size_t)128 * 1024 * 2;
    bf16* wihT_b = (bf16*)(ws + o); o += (size_t)128 * 1024 * 2;
    bf16* wp_f   = (bf16*)(ws + o); o += (size_t)256 * 1024 * 2;
    bf16* wp_b   = (bf16*)(ws + o); o += (size_t)256 * 1024 * 2;
    bf16* igq_f  = (bf16*)(ws + o); o += (size_t)S_ * B_ * 1024 * 2;
    bf16* igq_b  = (bf16*)(ws + o); o += (size_t)S_ * B_ * 1024 * 2;
    float* hf    = (float*)(ws + o); o += (size_t)S_ * B_ * 256 * 4;
    float* hb    = (float*)(ws + o); o += (size_t)S_ * B_ * 256 * 4;
    float* tag   = (float*)(ws + o); o += (size_t)B_ * T_ * S_ * 4;

    k_transpose<<<512, 256, 0, stream>>>(wih_f, wihT_f, 1024, 128);
    k_transpose<<<512, 256, 0, stream>>>(wih_b, wihT_b, 1024, 128);
    k_pack_whh<<<1024, 256, 0, stream>>>(whh_f, wp_f);
    k_pack_whh<<<1024, 256, 0, stream>>>(whh_b, wp_b);
    k_input_proj<<<dim3(1024, 2), 256, 0, stream>>>(word_ids, word_emb,
                                                    wihT_f, b_f, wihT_b, b_b, igq_f, igq_b);
    k_charcnn<<<B_ * S_, 64, 0, stream>>>(char_ids, char_emb, cnn_w, cnn_b,
                                          out + (size_t)B_ * S_ * T_);
    k_lstm_rec<<<128, 1024, 0, stream>>>(igq_f, igq_b, (const uint4*)wp_f, (const uint4*)wp_b,
                                         hf, hb);
    k_tag_linear<<<B_ * S_, 64, 0, stream>>>(hf, hb, out_w, out_b, tag);
    k_log_softmax<<<(B_ * T_ + 3) / 4, 256, 0, stream>>>(tag, out);
}

// Round 13
// 513.471 us; speedup vs baseline: 1.0002x; 1.0002x over previous
//
#include <hip/hip_runtime.h>
#include <hip/hip_bf16.h>

#define B_  64
#define S_  128
#define WP_ 18
#define K_  3
#define E_  128
#define H_  256
#define L_  4
#define T_  50

typedef __hip_bfloat16 bf16;

__device__ __forceinline__ float b2f(bf16 x) { return __bfloat162float(x); }
__device__ __forceinline__ bf16  f2b(float x) { return __float2bfloat16(x); }

__device__ __forceinline__ float fast_sigmoid(float x) {
    return 1.f / (1.f + __expf(-x));
}
__device__ __forceinline__ float fast_tanh(float x) {
    float a = fminf(fmaxf(2.f * x, -30.f), 30.f);
    float e = __expf(a);
    return (e - 1.f) / (e + 1.f);
}

// v_dot2_f32_bf16: z += lo(w)*lo(h) + hi(w)*hi(h), all ops one VALU inst
#define DOT2(z, w, h) asm("v_dot2_f32_bf16 %0, %1, %2, %0" : "+v"(z) : "v"(w), "v"(h))
// opaque pin: value becomes non-rematerializable (compiler must keep it in VGPRs)
// NOTE: parameter name must not collide with vector member names (.x .y .z .w)
#define PIN4(V_) asm volatile("" : "+v"((V_).x), "+v"((V_).y), "+v"((V_).z), "+v"((V_).w))

// ---------------------------------------------------------------- transpose (f32 -> bf16)
__global__ void k_transpose(const float* __restrict__ src, bf16* __restrict__ dst,
                            int R, int C) {
    int i = blockIdx.x * 256 + threadIdx.x;
    if (i >= R * C) return;
    int r = i / C, c = i % C;
    dst[c * R + r] = f2b(src[i]);
}

// ---------------------------------------------------------------- pack Whh for k-split layout
// thread (i,p) [t=i*4+p] needs w[col=g*256+i][k=64p..64p+63] as 8 uint4 (m=g*8+kk).
// dst uint4 index = m*1024 + t; bf16 element e = k&7.
__global__ void k_pack_whh(const float* __restrict__ src, bf16* __restrict__ dst) {
    int idx = blockIdx.x * 256 + threadIdx.x;   // over 1024*256
    if (idx >= 1024 * 256) return;
    int col = idx >> 8, k = idx & 255;
    int g = col >> 8, i = col & 255;
    int p = k >> 6, kk = (k >> 3) & 7, e = k & 7;
    int t = i * 4 + p, m = g * 8 + kk;
    dst[((size_t)(m * 1024 + t) << 3) + e] = f2b(src[col * 256 + k]);
}

// ---------------------------------------------------------------- char CNN
__global__ void k_charcnn(const int* __restrict__ char_ids,
                          const float* __restrict__ char_emb,
                          const float* __restrict__ cnn_w,
                          const float* __restrict__ cnn_b,
                          float* __restrict__ out_char) {
    const int CE_S = 132;
    const int W_S  = 388;
    __shared__ float ce[WP_ * 132];
    __shared__ float w[L_ * 388];
    __shared__ float bias[L_];
    int idx = blockIdx.x;            // b*S + s
    int t   = threadIdx.x;           // 0..63
    const int* ids = char_ids + idx * WP_;
    for (int i = t; i < WP_ * E_; i += 64) {
        int r = i >> 7, e = i & 127;
        ce[r * CE_S + e] = char_emb[ids[r] * E_ + e];
    }
    for (int i = t; i < L_ * K_ * E_; i += 64) {
        int r = i / (K_ * E_), e = i % (K_ * E_);
        w[r * W_S + e] = cnn_w[i];
    }
    if (t < L_) bias[t] = cnn_b[t];
    __syncthreads();
    int pos = t >> 2, c = t & 3;     // 16 positions x 4 channels
    float acc = 0.f;
    const float* wr = &w[c * W_S];
    #pragma unroll
    for (int i = 0; i < K_; ++i) {
        const float* cr = &ce[(pos + i) * CE_S];
        #pragma unroll 8
        for (int e = 0; e < E_; ++e) acc = fmaf(cr[e], wr[i * E_ + e], acc);
    }
    acc += bias[c];
    #pragma unroll
    for (int off = 4; off < 64; off <<= 1) acc = fmaxf(acc, __shfl_xor(acc, off));
    if (t < L_) out_char[idx * L_ + t] = acc;
}

// ---------------------------------------------------------------- input proj (16 rows/block)
// igq[row*1024 + i*4 + g] = b[g*256+i] + sum_k we[row,k]*WihT[k, g*256+i]
__global__ void k_input_proj(const int* __restrict__ word_ids,
                             const float* __restrict__ word_emb,
                             const bf16* __restrict__ wihT_f, const float* __restrict__ b_f,
                             const bf16* __restrict__ wihT_b, const float* __restrict__ b_b,
                             bf16* __restrict__ igq_f, bf16* __restrict__ igq_b) {
    int dir = blockIdx.y;
    const bf16* wihT = dir ? wihT_b : wihT_f;
    const float* bb  = dir ? b_b    : b_f;
    bf16* igq        = dir ? igq_b  : igq_f;
    __shared__ float x[16][128];
    int t  = threadIdx.x;            // 0..255 = unit i
    int r0 = blockIdx.x * 16;        // 16 rows (s*B+b) per block
    for (int i = t; i < 16 * 128; i += 256) {
        int rr = i >> 7, e = i & 127;
        int r = r0 + rr;
        int s = r >> 6, b = r & 63;
        int wid = word_ids[b * S_ + s];
        x[rr][e] = word_emb[(size_t)wid * E_ + e];
    }
    __syncthreads();
    int j = t;
    float acc[4][16];
    #pragma unroll
    for (int cj = 0; cj < 4; ++cj) {
        float bv = bb[j + cj * 256];
        #pragma unroll
        for (int rr = 0; rr < 16; ++rr) acc[cj][rr] = bv;
    }
    for (int k = 0; k < 128; ++k) {
        float wv[4];
        #pragma unroll
        for (int cj = 0; cj < 4; ++cj) wv[cj] = b2f(wihT[k * 1024 + j + cj * 256]);
        #pragma unroll
        for (int rr = 0; rr < 16; ++rr) {
            float xv = x[rr][k];
            #pragma unroll
            for (int cj = 0; cj < 4; ++cj) acc[cj][rr] = fmaf(xv, wv[cj], acc[cj][rr]);
        }
    }
    #pragma unroll
    for (int cj = 0; cj < 4; ++cj)
        #pragma unroll
        for (int rr = 0; rr < 16; ++rr)
            igq[(size_t)(r0 + rr) * 1024 + j * 4 + cj] = f2b(acc[cj][rr]);
}

// ---------------------------------------------------------------- recurrence (k-split + dot2)
// One block per (batch, direction). Thread t: unit i=t>>2, k-slice p=t&3.
// Tiers: m=0..11 pinned in VGPRs (48, opaque-asm so no remat), m=12..18 LDS
// (112 KB), m=19..31 streamed from L2 (208 KB/step) issued upfront.
__global__ __launch_bounds__(1024, 4) void k_lstm_rec(
        const bf16* __restrict__ igq_f, const bf16* __restrict__ igq_b,
        const uint4* __restrict__ wp_f, const uint4* __restrict__ wp_b,
        float* __restrict__ hf, float* __restrict__ hb) {
    __shared__ uint4 wlds[7168];                    // 112 KiB, m = 12..18
    __shared__ __align__(16) unsigned int hpbuf[2][160];  // padded bf16-pair h, dbuf

    int b   = blockIdx.x & 63;
    int dir = blockIdx.x >> 6;
    const bf16* igq = dir ? igq_b : igq_f;
    const uint4* wp = dir ? wp_b  : wp_f;
    float* hs       = dir ? hb    : hf;

    int t = threadIdx.x;
    int i = t >> 2, p = t & 3;

    for (int u = t; u < 7168; u += 1024) wlds[u] = wp[12 * 1024 + u];
    if (t < 320) ((unsigned int*)hpbuf)[t] = 0;
    float c_reg = 0.f;

    // register tier: m = 0..11, pinned so the compiler cannot rematerialize
    uint4 wreg[12];
    #pragma unroll
    for (int m = 0; m < 12; ++m) {
        wreg[m] = wp[m * 1024 + t];
        PIN4(wreg[m]);
    }
    __syncthreads();

    int cur = 0;
    int s0 = dir ? (S_ - 1) : 0;
    uint2 igu = *(const uint2*)&igq[((size_t)s0 * B_ + b) * 1024 + i * 4];

    for (int step = 0; step < S_; ++step) {
        int s = dir ? (S_ - 1 - step) : step;

        // issue ALL 13 streamed weight loads upfront (m=19..23, 24..31)
        uint4 ga[5], gb[8];
        #pragma unroll
        for (int u = 0; u < 5; ++u) ga[u] = wp[(19 + u) * 1024 + t];
        #pragma unroll
        for (int u = 0; u < 8; ++u) gb[u] = wp[(24 + u) * 1024 + t];

        float z0 = 0.f, z1 = 0.f, z2 = 0.f, z3 = 0.f;
        if (p == 0) {                       // seed ig term exactly once
            z0 = __uint_as_float(igu.x << 16);
            z1 = __uint_as_float(igu.x & 0xffff0000u);
            z2 = __uint_as_float(igu.y << 16);
            z3 = __uint_as_float(igu.y & 0xffff0000u);
        }
        const char* hpc = (const char*)hpbuf[cur];
        #pragma unroll
        for (int kk = 0; kk < 8; ++kk) {
            uint4 hv = *(const uint4*)(hpc + p * 144 + kk * 16);
            {   // g = 0, m = kk  -> registers
                uint4 wv = wreg[kk];
                DOT2(z0, wv.x, hv.x); DOT2(z0, wv.y, hv.y);
                DOT2(z0, wv.z, hv.z); DOT2(z0, wv.w, hv.w);
            }
            {   // g = 1, m = 8+kk -> kk<4: registers (m=8..11); else LDS (m=12..15)
                uint4 wv = (kk < 4) ? wreg[8 + kk] : wlds[(kk - 4) * 1024 + t];
                DOT2(z1, wv.x, hv.x); DOT2(z1, wv.y, hv.y);
                DOT2(z1, wv.z, hv.z); DOT2(z1, wv.w, hv.w);
            }
            {   // g = 2, m = 16+kk -> kk<3: LDS (m=16..18); else streamed (m=19..23)
                uint4 wv = (kk < 3) ? wlds[(4 + kk) * 1024 + t] : ga[kk - 3];
                DOT2(z2, wv.x, hv.x); DOT2(z2, wv.y, hv.y);
                DOT2(z2, wv.z, hv.z); DOT2(z2, wv.w, hv.w);
            }
            {   // g = 3, m = 24+kk -> streamed
                uint4 wv = gb[kk];
                DOT2(z3, wv.x, hv.x); DOT2(z3, wv.y, hv.y);
                DOT2(z3, wv.z, hv.z); DOT2(z3, wv.w, hv.w);
            }
        }
        // prefetch next step's ig quad (hides L2 latency under reduce/gates)
        if (step + 1 < S_) {
            int sn = dir ? (S_ - 2 - step) : (step + 1);
            igu = *(const uint2*)&igq[((size_t)sn * B_ + b) * 1024 + i * 4];
        }
        // butterfly sum across p (lanes differing in bits 0-1)
        z0 += __shfl_xor(z0, 1); z0 += __shfl_xor(z0, 2);
        z1 += __shfl_xor(z1, 1); z1 += __shfl_xor(z1, 2);
        z2 += __shfl_xor(z2, 1); z2 += __shfl_xor(z2, 2);
        z3 += __shfl_xor(z3, 1); z3 += __shfl_xor(z3, 2);
        if (p == 0) {
            float si = fast_sigmoid(z0);
            float sf = fast_sigmoid(z1);
            float tg = fast_tanh(z2);
            float so = fast_sigmoid(z3);
            c_reg = sf * c_reg + si * tg;
            float hn = so * fast_tanh(c_reg);
            hs[((size_t)s * B_ + b) * 256 + i] = hn;
            // store bf16 h into next buffer: seg (i>>6), pair (i>>1)&31, half (i&1)
            char* dstb = (char*)hpbuf[cur ^ 1] + (i >> 6) * 144 + ((i >> 1) & 31) * 4 + (i & 1) * 2;
            *(bf16*)dstb = f2b(hn);
        }
        __syncthreads();
        cur ^= 1;
    }
}

// ---------------------------------------------------------------- tag linear (4 words/block)
__global__ void k_tag_linear(const float* __restrict__ hf, const float* __restrict__ hb,
                             const float* __restrict__ out_w, const float* __restrict__ out_b,
                             float* __restrict__ tag) {
    __shared__ float hv[4][512];
    int bs0 = blockIdx.x * 4;        // 4 (b,s) words per block
    int t = threadIdx.x;             // 0..255
    for (int u = t; u < 4 * 256; u += 256) {
        int w = u >> 8, i2 = u & 255;
        int bs = bs0 + w;
        int b = bs >> 7, s = bs & 127;
        hv[w][i2]       = hf[((size_t)s * B_ + b) * 256 + i2];
        hv[w][256 + i2] = hb[((size_t)s * B_ + b) * 256 + i2];
    }
    __syncthreads();
    int w = t >> 6, tt = t & 63;
    if (tt < T_) {
        int bs = bs0 + w;
        int b = bs >> 7, s = bs & 127;
        float acc = out_b[tt];
        #pragma unroll 8
        for (int k = 0; k < 512; ++k) acc = fmaf(hv[w][k], out_w[tt * 512 + k], acc);
        tag[((size_t)b * T_ + tt) * S_ + s] = acc;
    }
}

// ---------------------------------------------------------------- log_softmax over S (axis=1)
__global__ void k_log_softmax(const float* __restrict__ tag, float* __restrict__ out) {
    int wid  = (blockIdx.x * 256 + threadIdx.x) >> 6;   // one wave per (b,t)
    int lane = threadIdx.x & 63;
    if (wid >= B_ * T_) return;
    int b = wid / T_, t = wid % T_;
    const float* row = tag + (size_t)wid * S_;
    float v0 = row[lane], v1 = row[lane + 64];
    float m = fmaxf(v0, v1);
    #pragma unroll
    for (int off = 32; off; off >>= 1) m = fmaxf(m, __shfl_xor(m, off));
    float e = expf(v0 - m) + expf(v1 - m);
    #pragma unroll
    for (int off = 32; off; off >>= 1) e += __shfl_xor(e, off);
    float lse = m + logf(e);
    out[((size_t)b * S_ + lane)      * T_ + t] = v0 - lse;
    out[((size_t)b * S_ + lane + 64) * T_ + t] = v1 - lse;
}

// ---------------------------------------------------------------- launch
extern "C" void kernel_launch(void* const* d_in, const int* in_sizes, int n_in,
                              void* d_out, int out_size, void* d_ws, size_t ws_size,
                              hipStream_t stream) {
    const int*   char_ids = (const int*)d_in[0];
    const int*   word_ids = (const int*)d_in[1];
    const float* char_emb = (const float*)d_in[2];
    const float* word_emb = (const float*)d_in[3];
    const float* cnn_w    = (const float*)d_in[4];
    const float* cnn_b    = (const float*)d_in[5];
    const float* wih_f    = (const float*)d_in[6];
    const float* whh_f    = (const float*)d_in[7];
    const float* b_f      = (const float*)d_in[8];
    const float* wih_b    = (const float*)d_in[9];
    const float* whh_b    = (const float*)d_in[10];
    const float* b_b      = (const float*)d_in[11];
    const float* out_w    = (const float*)d_in[12];
    const float* out_b    = (const float*)d_in[13];
    float* out = (float*)d_out;
    char* ws   = (char*)d_ws;

    size_t o = 0;
    bf16* wihT_f = (bf16*)(ws + o); o += (size_t)128 * 1024 * 2;
    bf16* wihT_b = (bf16*)(ws + o); o += (size_t)128 * 1024 * 2;
    bf16* wp_f   = (bf16*)(ws + o); o += (size_t)256 * 1024 * 2;
    bf16* wp_b   = (bf16*)(ws + o); o += (size_t)256 * 1024 * 2;
    bf16* igq_f  = (bf16*)(ws + o); o += (size_t)S_ * B_ * 1024 * 2;
    bf16* igq_b  = (bf16*)(ws + o); o += (size_t)S_ * B_ * 1024 * 2;
    float* hf    = (float*)(ws + o); o += (size_t)S_ * B_ * 256 * 4;
    float* hb    = (float*)(ws + o); o += (size_t)S_ * B_ * 256 * 4;
    float* tag   = (float*)(ws + o); o += (size_t)B_ * T_ * S_ * 4;

    k_transpose<<<512, 256, 0, stream>>>(wih_f, wihT_f, 1024, 128);
    k_transpose<<<512, 256, 0, stream>>>(wih_b, wihT_b, 1024, 128);
    k_pack_whh<<<1024, 256, 0, stream>>>(whh_f, wp_f);
    k_pack_whh<<<1024, 256, 0, stream>>>(whh_b, wp_b);
    k_input_proj<<<dim3(512, 2), 256, 0, stream>>>(word_ids, word_emb,
                                                   wihT_f, b_f, wihT_b, b_b, igq_f, igq_b);
    k_charcnn<<<B_ * S_, 64, 0, stream>>>(char_ids, char_emb, cnn_w, cnn_b,
                                          out + (size_t)B_ * S_ * T_);
    k_lstm_rec<<<128, 1024, 0, stream>>>(igq_f, igq_b, (const uint4*)wp_f, (const uint4*)wp_b,
                                         hf, hb);
    k_tag_linear<<<B_ * S_ / 4, 256, 0, stream>>>(hf, hb, out_w, out_b, tag);
    k_log_softmax<<<(B_ * T_ + 3) / 4, 256, 0, stream>>>(tag, out);
}

// Round 14
// 488.827 us; speedup vs baseline: 1.0507x; 1.0504x over previous
//
#include <hip/hip_runtime.h>
#include <hip/hip_bf16.h>

#define B_  64
#define S_  128
#define WP_ 18
#define K_  3
#define E_  128
#define H_  256
#define L_  4
#define T_  50

typedef __hip_bfloat16 bf16;

__device__ __forceinline__ float b2f(bf16 x) { return __bfloat162float(x); }
__device__ __forceinline__ bf16  f2b(float x) { return __float2bfloat16(x); }

__device__ __forceinline__ float fast_sigmoid(float x) {
    return 1.f / (1.f + __expf(-x));
}
__device__ __forceinline__ float fast_tanh(float x) {
    float a = fminf(fmaxf(2.f * x, -30.f), 30.f);
    float e = __expf(a);
    return (e - 1.f) / (e + 1.f);
}

// v_dot2_f32_bf16: z += lo(w)*lo(h) + hi(w)*hi(h), all ops one VALU inst
#define DOT2(z, w, h) asm("v_dot2_f32_bf16 %0, %1, %2, %0" : "+v"(z) : "v"(w), "v"(h))
// opaque pin: value becomes non-rematerializable (compiler must keep it in VGPRs)
// NOTE: parameter name must not collide with vector member names (.x .y .z .w)
#define PIN4(V_) asm volatile("" : "+v"((V_).x), "+v"((V_).y), "+v"((V_).z), "+v"((V_).w))

// ---------------------------------------------------------------- transpose (f32 -> bf16)
__global__ void k_transpose(const float* __restrict__ src, bf16* __restrict__ dst,
                            int R, int C) {
    int i = blockIdx.x * 256 + threadIdx.x;
    if (i >= R * C) return;
    int r = i / C, c = i % C;
    dst[c * R + r] = f2b(src[i]);
}

// ---------------------------------------------------------------- pack Whh for k-split layout
// thread (i,p) [t=i*4+p] needs w[col=g*256+i][k=64p..64p+63] as 8 uint4 (m=g*8+kk).
// dst uint4 index = m*1024 + t; bf16 element e = k&7.
__global__ void k_pack_whh(const float* __restrict__ src, bf16* __restrict__ dst) {
    int idx = blockIdx.x * 256 + threadIdx.x;   // over 1024*256
    if (idx >= 1024 * 256) return;
    int col = idx >> 8, k = idx & 255;
    int g = col >> 8, i = col & 255;
    int p = k >> 6, kk = (k >> 3) & 7, e = k & 7;
    int t = i * 4 + p, m = g * 8 + kk;
    dst[((size_t)(m * 1024 + t) << 3) + e] = f2b(src[col * 256 + k]);
}

// ---------------------------------------------------------------- char CNN
__global__ void k_charcnn(const int* __restrict__ char_ids,
                          const float* __restrict__ char_emb,
                          const float* __restrict__ cnn_w,
                          const float* __restrict__ cnn_b,
                          float* __restrict__ out_char) {
    const int CE_S = 132;
    const int W_S  = 388;
    __shared__ float ce[WP_ * 132];
    __shared__ float w[L_ * 388];
    __shared__ float bias[L_];
    int idx = blockIdx.x;            // b*S + s
    int t   = threadIdx.x;           // 0..63
    const int* ids = char_ids + idx * WP_;
    for (int i = t; i < WP_ * E_; i += 64) {
        int r = i >> 7, e = i & 127;
        ce[r * CE_S + e] = char_emb[ids[r] * E_ + e];
    }
    for (int i = t; i < L_ * K_ * E_; i += 64) {
        int r = i / (K_ * E_), e = i % (K_ * E_);
        w[r * W_S + e] = cnn_w[i];
    }
    if (t < L_) bias[t] = cnn_b[t];
    __syncthreads();
    int pos = t >> 2, c = t & 3;     // 16 positions x 4 channels
    float acc = 0.f;
    const float* wr = &w[c * W_S];
    #pragma unroll
    for (int i = 0; i < K_; ++i) {
        const float* cr = &ce[(pos + i) * CE_S];
        #pragma unroll 8
        for (int e = 0; e < E_; ++e) acc = fmaf(cr[e], wr[i * E_ + e], acc);
    }
    acc += bias[c];
    #pragma unroll
    for (int off = 4; off < 64; off <<= 1) acc = fmaxf(acc, __shfl_xor(acc, off));
    if (t < L_) out_char[idx * L_ + t] = acc;
}

// ---------------------------------------------------------------- input proj (16 rows/block)
// igq[row*1024 + i*4 + g] = b[g*256+i] + sum_k we[row,k]*WihT[k, g*256+i]
__global__ void k_input_proj(const int* __restrict__ word_ids,
                             const float* __restrict__ word_emb,
                             const bf16* __restrict__ wihT_f, const float* __restrict__ b_f,
                             const bf16* __restrict__ wihT_b, const float* __restrict__ b_b,
                             bf16* __restrict__ igq_f, bf16* __restrict__ igq_b) {
    int dir = blockIdx.y;
    const bf16* wihT = dir ? wihT_b : wihT_f;
    const float* bb  = dir ? b_b    : b_f;
    bf16* igq        = dir ? igq_b  : igq_f;
    __shared__ float x[16][128];
    int t  = threadIdx.x;            // 0..255 = unit i
    int r0 = blockIdx.x * 16;        // 16 rows (s*B+b) per block
    for (int i = t; i < 16 * 128; i += 256) {
        int rr = i >> 7, e = i & 127;
        int r = r0 + rr;
        int s = r >> 6, b = r & 63;
        int wid = word_ids[b * S_ + s];
        x[rr][e] = word_emb[(size_t)wid * E_ + e];
    }
    __syncthreads();
    int j = t;
    float acc[4][16];
    #pragma unroll
    for (int cj = 0; cj < 4; ++cj) {
        float bv = bb[j + cj * 256];
        #pragma unroll
        for (int rr = 0; rr < 16; ++rr) acc[cj][rr] = bv;
    }
    for (int k = 0; k < 128; ++k) {
        float wv[4];
        #pragma unroll
        for (int cj = 0; cj < 4; ++cj) wv[cj] = b2f(wihT[k * 1024 + j + cj * 256]);
        #pragma unroll
        for (int rr = 0; rr < 16; ++rr) {
            float xv = x[rr][k];
            #pragma unroll
            for (int cj = 0; cj < 4; ++cj) acc[cj][rr] = fmaf(xv, wv[cj], acc[cj][rr]);
        }
    }
    #pragma unroll
    for (int cj = 0; cj < 4; ++cj)
        #pragma unroll
        for (int rr = 0; rr < 16; ++rr)
            igq[(size_t)(r0 + rr) * 1024 + j * 4 + cj] = f2b(acc[cj][rr]);
}

// ---------------------------------------------------------------- recurrence (k-split + dot2)
// One block per (batch, direction). Thread t: unit i=t>>2, k-slice p=t&3.
// FULLY WEIGHT-RESIDENT: m=0..22 pinned in VGPRs (92 regs), m=23..31 in LDS
// (144 KB). ZERO global weight traffic in the step loop.
__global__ __launch_bounds__(1024, 4) void k_lstm_rec(
        const bf16* __restrict__ igq_f, const bf16* __restrict__ igq_b,
        const uint4* __restrict__ wp_f, const uint4* __restrict__ wp_b,
        float* __restrict__ hf, float* __restrict__ hb) {
    __shared__ uint4 wlds[9216];                    // 144 KiB, m = 23..31
    __shared__ __align__(16) unsigned int hpbuf[2][160];  // padded bf16-pair h, dbuf

    int b   = blockIdx.x & 63;
    int dir = blockIdx.x >> 6;
    const bf16* igq = dir ? igq_b : igq_f;
    const uint4* wp = dir ? wp_b  : wp_f;
    float* hs       = dir ? hb    : hf;

    int t = threadIdx.x;
    int i = t >> 2, p = t & 3;

    for (int u = t; u < 9216; u += 1024) wlds[u] = wp[23 * 1024 + u];
    if (t < 320) ((unsigned int*)hpbuf)[t] = 0;
    float c_reg = 0.f;

    // register tier: m = 0..22 fully resident (92 VGPRs), pinned vs remat
    uint4 wreg[23];
    #pragma unroll
    for (int m = 0; m < 23; ++m) {
        wreg[m] = wp[m * 1024 + t];
        PIN4(wreg[m]);
    }
    __syncthreads();

    int cur = 0;
    int s0 = dir ? (S_ - 1) : 0;
    uint2 igu = *(const uint2*)&igq[((size_t)s0 * B_ + b) * 1024 + i * 4];

    for (int step = 0; step < S_; ++step) {
        int s = dir ? (S_ - 1 - step) : step;

        float z0 = 0.f, z1 = 0.f, z2 = 0.f, z3 = 0.f;
        if (p == 0) {                       // seed ig term exactly once
            z0 = __uint_as_float(igu.x << 16);
            z1 = __uint_as_float(igu.x & 0xffff0000u);
            z2 = __uint_as_float(igu.y << 16);
            z3 = __uint_as_float(igu.y & 0xffff0000u);
        }
        const char* hpc = (const char*)hpbuf[cur];
        #pragma unroll
        for (int kk = 0; kk < 8; ++kk) {
            uint4 hv = *(const uint4*)(hpc + p * 144 + kk * 16);
            {   // g = 0, m = kk  -> registers
                uint4 wv = wreg[kk];
                DOT2(z0, wv.x, hv.x); DOT2(z0, wv.y, hv.y);
                DOT2(z0, wv.z, hv.z); DOT2(z0, wv.w, hv.w);
            }
            {   // g = 1, m = 8+kk -> registers
                uint4 wv = wreg[8 + kk];
                DOT2(z1, wv.x, hv.x); DOT2(z1, wv.y, hv.y);
                DOT2(z1, wv.z, hv.z); DOT2(z1, wv.w, hv.w);
            }
            {   // g = 2, m = 16+kk -> kk<7: registers (m=16..22); kk==7: LDS (m=23)
                uint4 wv = (kk < 7) ? wreg[16 + kk] : wlds[t];
                DOT2(z2, wv.x, hv.x); DOT2(z2, wv.y, hv.y);
                DOT2(z2, wv.z, hv.z); DOT2(z2, wv.w, hv.w);
            }
            {   // g = 3, m = 24+kk -> LDS (idx 1..8)
                uint4 wv = wlds[(1 + kk) * 1024 + t];
                DOT2(z3, wv.x, hv.x); DOT2(z3, wv.y, hv.y);
                DOT2(z3, wv.z, hv.z); DOT2(z3, wv.w, hv.w);
            }
        }
        // prefetch next step's ig quad (hides L2 latency under reduce/gates)
        if (step + 1 < S_) {
            int sn = dir ? (S_ - 2 - step) : (step + 1);
            igu = *(const uint2*)&igq[((size_t)sn * B_ + b) * 1024 + i * 4];
        }
        // butterfly sum across p (lanes differing in bits 0-1)
        z0 += __shfl_xor(z0, 1); z0 += __shfl_xor(z0, 2);
        z1 += __shfl_xor(z1, 1); z1 += __shfl_xor(z1, 2);
        z2 += __shfl_xor(z2, 1); z2 += __shfl_xor(z2, 2);
        z3 += __shfl_xor(z3, 1); z3 += __shfl_xor(z3, 2);
        if (p == 0) {
            float si = fast_sigmoid(z0);
            float sf = fast_sigmoid(z1);
            float tg = fast_tanh(z2);
            float so = fast_sigmoid(z3);
            c_reg = sf * c_reg + si * tg;
            float hn = so * fast_tanh(c_reg);
            hs[((size_t)s * B_ + b) * 256 + i] = hn;
            // store bf16 h into next buffer: seg (i>>6), pair (i>>1)&31, half (i&1)
            char* dstb = (char*)hpbuf[cur ^ 1] + (i >> 6) * 144 + ((i >> 1) & 31) * 4 + (i & 1) * 2;
            *(bf16*)dstb = f2b(hn);
        }
        __syncthreads();
        cur ^= 1;
    }
}

// ---------------------------------------------------------------- tag linear (4 words/block)
__global__ void k_tag_linear(const float* __restrict__ hf, const float* __restrict__ hb,
                             const float* __restrict__ out_w, const float* __restrict__ out_b,
                             float* __restrict__ tag) {
    __shared__ float hv[4][512];
    int bs0 = blockIdx.x * 4;        // 4 (b,s) words per block
    int t = threadIdx.x;             // 0..255
    for (int u = t; u < 4 * 256; u += 256) {
        int w = u >> 8, i2 = u & 255;
        int bs = bs0 + w;
        int b = bs >> 7, s = bs & 127;
        hv[w][i2]       = hf[((size_t)s * B_ + b) * 256 + i2];
        hv[w][256 + i2] = hb[((size_t)s * B_ + b) * 256 + i2];
    }
    __syncthreads();
    int w = t >> 6, tt = t & 63;
    if (tt < T_) {
        int bs = bs0 + w;
        int b = bs >> 7, s = bs & 127;
        float acc = out_b[tt];
        #pragma unroll 8
        for (int k = 0; k < 512; ++k) acc = fmaf(hv[w][k], out_w[tt * 512 + k], acc);
        tag[((size_t)b * T_ + tt) * S_ + s] = acc;
    }
}

// ---------------------------------------------------------------- log_softmax over S (axis=1)
__global__ void k_log_softmax(const float* __restrict__ tag, float* __restrict__ out) {
    int wid  = (blockIdx.x * 256 + threadIdx.x) >> 6;   // one wave per (b,t)
    int lane = threadIdx.x & 63;
    if (wid >= B_ * T_) return;
    int b = wid / T_, t = wid % T_;
    const float* row = tag + (size_t)wid * S_;
    float v0 = row[lane], v1 = row[lane + 64];
    float m = fmaxf(v0, v1);
    #pragma unroll
    for (int off = 32; off; off >>= 1) m = fmaxf(m, __shfl_xor(m, off));
    float e = expf(v0 - m) + expf(v1 - m);
    #pragma unroll
    for (int off = 32; off; off >>= 1) e += __shfl_xor(e, off);
    float lse = m + logf(e);
    out[((size_t)b * S_ + lane)      * T_ + t] = v0 - lse;
    out[((size_t)b * S_ + lane + 64) * T_ + t] = v1 - lse;
}

// ---------------------------------------------------------------- launch
extern "C" void kernel_launch(void* const* d_in, const int* in_sizes, int n_in,
                              void* d_out, int out_size, void* d_ws, size_t ws_size,
                              hipStream_t stream) {
    const int*   char_ids = (const int*)d_in[0];
    const int*   word_ids = (const int*)d_in[1];
    const float* char_emb = (const float*)d_in[2];
    const float* word_emb = (const float*)d_in[3];
    const float* cnn_w    = (const float*)d_in[4];
    const float* cnn_b    = (const float*)d_in[5];
    const float* wih_f    = (const float*)d_in[6];
    const float* whh_f    = (const float*)d_in[7];
    const float* b_f      = (const float*)d_in[8];
    const float* wih_b    = (const float*)d_in[9];
    const float* whh_b    = (const float*)d_in[10];
    const float* b_b      = (const float*)d_in[11];
    const float* out_w    = (const float*)d_in[12];
    const float* out_b    = (const float*)d_in[13];
    float* out = (float*)d_out;
    char* ws   = (char*)d_ws;

    size_t o = 0;
    bf16* wihT_f = (bf16*)(ws + o); o += (size_t)128 * 1024 * 2;
    bf16* wihT_b = (bf16*)(ws + o); o += (size_t)128 * 1024 * 2;
    bf16* wp_f   = (bf16*)(ws + o); o += (size_t)256 * 1024 * 2;
    bf16* wp_b   = (bf16*)(ws + o); o += (size_t)256 * 1024 * 2;
    bf16* igq_f  = (bf16*)(ws + o); o += (size_t)S_ * B_ * 1024 * 2;
    bf16* igq_b  = (bf16*)(ws + o); o += (size_t)S_ * B_ * 1024 * 2;
    float* hf    = (float*)(ws + o); o += (size_t)S_ * B_ * 256 * 4;
    float* hb    = (float*)(ws + o); o += (size_t)S_ * B_ * 256 * 4;
    float* tag   = (float*)(ws + o); o += (size_t)B_ * T_ * S_ * 4;

    k_transpose<<<512, 256, 0, stream>>>(wih_f, wihT_f, 1024, 128);
    k_transpose<<<512, 256, 0, stream>>>(wih_b, wihT_b, 1024, 128);
    k_pack_whh<<<1024, 256, 0, stream>>>(whh_f, wp_f);
    k_pack_whh<<<1024, 256, 0, stream>>>(whh_b, wp_b);
    k_input_proj<<<dim3(512, 2), 256, 0, stream>>>(word_ids, word_emb,
                                                   wihT_f, b_f, wihT_b, b_b, igq_f, igq_b);
    k_charcnn<<<B_ * S_, 64, 0, stream>>>(char_ids, char_emb, cnn_w, cnn_b,
                                          out + (size_t)B_ * S_ * T_);
    k_lstm_rec<<<128, 1024, 0, stream>>>(igq_f, igq_b, (const uint4*)wp_f, (const uint4*)wp_b,
                                         hf, hb);
    k_tag_linear<<<B_ * S_ / 4, 256, 0, stream>>>(hf, hb, out_w, out_b, tag);
    k_log_softmax<<<(B_ * T_ + 3) / 4, 256, 0, stream>>>(tag, out);
}

// Round 15
// 450.984 us; speedup vs baseline: 1.1388x; 1.0839x over previous
//
#include <hip/hip_runtime.h>
#include <hip/hip_bf16.h>

#define B_  64
#define S_  128
#define WP_ 18
#define K_  3
#define E_  128
#define H_  256
#define L_  4
#define T_  50

typedef __hip_bfloat16 bf16;

__device__ __forceinline__ float b2f(bf16 x) { return __bfloat162float(x); }
__device__ __forceinline__ bf16  f2b(float x) { return __float2bfloat16(x); }

__device__ __forceinline__ float fast_sigmoid(float x) {
    return 1.f / (1.f + __expf(-x));
}
__device__ __forceinline__ float fast_tanh(float x) {
    float a = fminf(fmaxf(2.f * x, -30.f), 30.f);
    float e = __expf(a);
    return (e - 1.f) / (e + 1.f);
}
__device__ __forceinline__ unsigned int pack2(float lo, float hi) {
    bf16 l = f2b(lo), h = f2b(hi);
    unsigned short ls = *(unsigned short*)&l, hs = *(unsigned short*)&h;
    return ((unsigned int)hs << 16) | ls;
}

// v_dot2_f32_bf16: z += lo(w)*lo(h) + hi(w)*hi(h), all ops one VALU inst
#define DOT2(z, w, h) asm("v_dot2_f32_bf16 %0, %1, %2, %0" : "+v"(z) : "v"(w), "v"(h))
// opaque pin: value becomes non-rematerializable
#define PIN4(V_) asm volatile("" : "+v"((V_).x), "+v"((V_).y), "+v"((V_).z), "+v"((V_).w))

// ---------------------------------------------------------------- prep1: transposes + packs (merged)
// blocks [0,512): pack whh_f | [512,1024): pack whh_b | [1024,1280): transpose wih_f | [1280,1536): wih_b
__global__ void k_prep1(const float* __restrict__ whh_f, const float* __restrict__ whh_b,
                        const float* __restrict__ wih_f, const float* __restrict__ wih_b,
                        bf16* __restrict__ wp_f, bf16* __restrict__ wp_b,
                        bf16* __restrict__ wihT_f, bf16* __restrict__ wihT_b) {
    int blk = blockIdx.x, t = threadIdx.x;
    if (blk < 1024) {
        const float* src = (blk < 512) ? whh_f : whh_b;
        bf16* dst        = (blk < 512) ? wp_f  : wp_b;
        int sub = blk & 511;
        int idx2 = ((sub << 8) + t) << 1;         // even element index over 1024*256
        int col = idx2 >> 8, k = idx2 & 255;      // k even
        int g = col >> 8, i = col & 255;
        int p = k >> 6, kk = (k >> 3) & 7, e = k & 7;
        int td = i * 4 + p, m = g * 8 + kk;
        float2 sv = *(const float2*)(src + col * 256 + k);
        bf16* dp = dst + (((size_t)(m * 1024 + td)) << 3) + e;
        dp[0] = f2b(sv.x);
        dp[1] = f2b(sv.y);
    } else {
        int id = blk - 1024;
        const float* src = (id < 256) ? wih_f  : wih_b;
        bf16* dst        = (id < 256) ? wihT_f : wihT_b;
        int sub = id & 255;
        int i2 = ((sub << 8) + t) << 1;           // over 1024*128, c even
        int r = i2 >> 7, c = i2 & 127;
        float2 sv = *(const float2*)(src + i2);
        dst[c * 1024 + r]       = f2b(sv.x);
        dst[(c + 1) * 1024 + r] = f2b(sv.y);
    }
}

// ---------------------------------------------------------------- input proj (16 rows/block)
__global__ void k_input_proj(const int* __restrict__ word_ids,
                             const float* __restrict__ word_emb,
                             const bf16* __restrict__ wihT_f, const float* __restrict__ b_f,
                             const bf16* __restrict__ wihT_b, const float* __restrict__ b_b,
                             bf16* __restrict__ igq_f, bf16* __restrict__ igq_b) {
    int dir = blockIdx.y;
    const bf16* wihT = dir ? wihT_b : wihT_f;
    const float* bb  = dir ? b_b    : b_f;
    bf16* igq        = dir ? igq_b  : igq_f;
    __shared__ float x[16][128];
    int t  = threadIdx.x;
    int r0 = blockIdx.x * 16;
    for (int i = t; i < 16 * 128; i += 256) {
        int rr = i >> 7, e = i & 127;
        int r = r0 + rr;
        int s = r >> 6, b = r & 63;
        int wid = word_ids[b * S_ + s];
        x[rr][e] = word_emb[(size_t)wid * E_ + e];
    }
    __syncthreads();
    int j = t;
    float acc[4][16];
    #pragma unroll
    for (int cj = 0; cj < 4; ++cj) {
        float bv = bb[j + cj * 256];
        #pragma unroll
        for (int rr = 0; rr < 16; ++rr) acc[cj][rr] = bv;
    }
    for (int k = 0; k < 128; ++k) {
        float wv[4];
        #pragma unroll
        for (int cj = 0; cj < 4; ++cj) wv[cj] = b2f(wihT[k * 1024 + j + cj * 256]);
        #pragma unroll
        for (int rr = 0; rr < 16; ++rr) {
            float xv = x[rr][k];
            #pragma unroll
            for (int cj = 0; cj < 4; ++cj) acc[cj][rr] = fmaf(xv, wv[cj], acc[cj][rr]);
        }
    }
    #pragma unroll
    for (int cj = 0; cj < 4; ++cj)
        #pragma unroll
        for (int rr = 0; rr < 16; ++rr)
            igq[(size_t)(r0 + rr) * 1024 + j * 4 + cj] = f2b(acc[cj][rr]);
}

// ---------------------------------------------------------------- fused recurrence + char CNN
// blocks [0,128): LSTM recurrence (1 chain each, as round 14).
// blocks [128,256): char CNN on the otherwise-idle CUs (16 waves x 4 words each),
// LDS carved out of the same wlds pool (bf16-pair ce + DOT2).
__global__ __launch_bounds__(1024, 4) void k_lstm_cnn(
        const bf16* __restrict__ igq_f, const bf16* __restrict__ igq_b,
        const uint4* __restrict__ wp_f, const uint4* __restrict__ wp_b,
        float* __restrict__ hf, float* __restrict__ hb,
        const int* __restrict__ char_ids, const float* __restrict__ char_emb,
        const float* __restrict__ cnn_w, const float* __restrict__ cnn_b,
        float* __restrict__ out_char) {
    __shared__ uint4 wlds[9216];                          // 144 KiB pool
    __shared__ __align__(16) unsigned int hpbuf[2][160];  // rec only

    int t = threadIdx.x;

    if (blockIdx.x < 128) {
        // ======================= LSTM recurrence (identical to round 14) ==
        int b   = blockIdx.x & 63;
        int dir = blockIdx.x >> 6;
        const bf16* igq = dir ? igq_b : igq_f;
        const uint4* wp = dir ? wp_b  : wp_f;
        float* hs       = dir ? hb    : hf;

        int i = t >> 2, p = t & 3;

        for (int u = t; u < 9216; u += 1024) wlds[u] = wp[23 * 1024 + u];
        if (t < 320) ((unsigned int*)hpbuf)[t] = 0;
        float c_reg = 0.f;

        uint4 wreg[23];
        #pragma unroll
        for (int m = 0; m < 23; ++m) {
            wreg[m] = wp[m * 1024 + t];
            PIN4(wreg[m]);
        }
        __syncthreads();

        int cur = 0;
        int s0 = dir ? (S_ - 1) : 0;
        uint2 igu = *(const uint2*)&igq[((size_t)s0 * B_ + b) * 1024 + i * 4];

        for (int step = 0; step < S_; ++step) {
            int s = dir ? (S_ - 1 - step) : step;

            float z0 = 0.f, z1 = 0.f, z2 = 0.f, z3 = 0.f;
            if (p == 0) {
                z0 = __uint_as_float(igu.x << 16);
                z1 = __uint_as_float(igu.x & 0xffff0000u);
                z2 = __uint_as_float(igu.y << 16);
                z3 = __uint_as_float(igu.y & 0xffff0000u);
            }
            const char* hpc = (const char*)hpbuf[cur];
            #pragma unroll
            for (int kk = 0; kk < 8; ++kk) {
                uint4 hv = *(const uint4*)(hpc + p * 144 + kk * 16);
                {   uint4 wv = wreg[kk];
                    DOT2(z0, wv.x, hv.x); DOT2(z0, wv.y, hv.y);
                    DOT2(z0, wv.z, hv.z); DOT2(z0, wv.w, hv.w); }
                {   uint4 wv = wreg[8 + kk];
                    DOT2(z1, wv.x, hv.x); DOT2(z1, wv.y, hv.y);
                    DOT2(z1, wv.z, hv.z); DOT2(z1, wv.w, hv.w); }
                {   uint4 wv = (kk < 7) ? wreg[16 + kk] : wlds[t];
                    DOT2(z2, wv.x, hv.x); DOT2(z2, wv.y, hv.y);
                    DOT2(z2, wv.z, hv.z); DOT2(z2, wv.w, hv.w); }
                {   uint4 wv = wlds[(1 + kk) * 1024 + t];
                    DOT2(z3, wv.x, hv.x); DOT2(z3, wv.y, hv.y);
                    DOT2(z3, wv.z, hv.z); DOT2(z3, wv.w, hv.w); }
            }
            if (step + 1 < S_) {
                int sn = dir ? (S_ - 2 - step) : (step + 1);
                igu = *(const uint2*)&igq[((size_t)sn * B_ + b) * 1024 + i * 4];
            }
            z0 += __shfl_xor(z0, 1); z0 += __shfl_xor(z0, 2);
            z1 += __shfl_xor(z1, 1); z1 += __shfl_xor(z1, 2);
            z2 += __shfl_xor(z2, 1); z2 += __shfl_xor(z2, 2);
            z3 += __shfl_xor(z3, 1); z3 += __shfl_xor(z3, 2);
            if (p == 0) {
                float si = fast_sigmoid(z0);
                float sf = fast_sigmoid(z1);
                float tg = fast_tanh(z2);
                float so = fast_sigmoid(z3);
                c_reg = sf * c_reg + si * tg;
                float hn = so * fast_tanh(c_reg);
                hs[((size_t)s * B_ + b) * 256 + i] = hn;
                char* dstb = (char*)hpbuf[cur ^ 1] + (i >> 6) * 144 + ((i >> 1) & 31) * 4 + (i & 1) * 2;
                *(bf16*)dstb = f2b(hn);
            }
            __syncthreads();
            cur ^= 1;
        }
    } else {
        // ======================= char CNN on idle CUs ======================
        // LDS layout in wlds (uints): w2 [4][196] @0, bias @784, ce2 @800 + wave*1224 ([18][68])
        unsigned int* pool_u = (unsigned int*)wlds;
        float*        pool_f = (float*)wlds;
        int blkc = blockIdx.x - 128;

        for (int u = t; u < 4 * 192; u += 1024) {
            int c = u / 192, pe = u % 192;
            pool_u[c * 196 + pe] = pack2(cnn_w[c * 384 + 2 * pe], cnn_w[c * 384 + 2 * pe + 1]);
        }
        if (t < 4) pool_f[784 + t] = cnn_b[t];
        __syncthreads();

        int wv = t >> 6, lane = t & 63;
        unsigned int* cew = pool_u + 800 + wv * 1224;
        int pos = lane >> 2, c = lane & 3;

        #pragma unroll 1
        for (int j = 0; j < 4; ++j) {
            int word = (blkc * 16 + wv) * 4 + j;
            const int* ids = char_ids + word * WP_;
            for (int row = 0; row < WP_; ++row) {
                float2 ev = *(const float2*)(char_emb + (size_t)ids[row] * 128 + 2 * lane);
                cew[row * 68 + lane] = pack2(ev.x, ev.y);
            }
            float acc = 0.f;
            #pragma unroll
            for (int i = 0; i < K_; ++i) {
                const uint4* cr = (const uint4*)(cew + (pos + i) * 68);
                const uint4* wr = (const uint4*)(pool_u + c * 196 + i * 64);
                #pragma unroll
                for (int q = 0; q < 16; ++q) {
                    uint4 cv = cr[q], wq = wr[q];
                    DOT2(acc, wq.x, cv.x); DOT2(acc, wq.y, cv.y);
                    DOT2(acc, wq.z, cv.z); DOT2(acc, wq.w, cv.w);
                }
            }
            acc += pool_f[784 + c];
            #pragma unroll
            for (int off = 4; off < 64; off <<= 1) acc = fmaxf(acc, __shfl_xor(acc, off));
            if (lane < L_) out_char[(size_t)word * L_ + lane] = acc;
        }
    }
}

// ---------------------------------------------------------------- tag linear (8 words/block)
__global__ void k_tag_linear(const float* __restrict__ hf, const float* __restrict__ hb,
                             const float* __restrict__ out_w, const float* __restrict__ out_b,
                             float* __restrict__ tag) {
    __shared__ float hv[8][512];
    int bs0 = blockIdx.x * 8;
    int t = threadIdx.x;             // 0..511
    for (int u = t; u < 8 * 256; u += 512) {
        int w = u >> 8, i2 = u & 255;
        int bs = bs0 + w;
        int b = bs >> 7, s = bs & 127;
        hv[w][i2]       = hf[((size_t)s * B_ + b) * 256 + i2];
        hv[w][256 + i2] = hb[((size_t)s * B_ + b) * 256 + i2];
    }
    __syncthreads();
    int w = t >> 6, tt = t & 63;
    if (tt < T_) {
        int bs = bs0 + w;
        int b = bs >> 7, s = bs & 127;
        float acc = out_b[tt];
        #pragma unroll 8
        for (int k = 0; k < 512; ++k) acc = fmaf(hv[w][k], out_w[tt * 512 + k], acc);
        tag[((size_t)b * T_ + tt) * S_ + s] = acc;
    }
}

// ---------------------------------------------------------------- log_softmax over S (axis=1)
__global__ void k_log_softmax(const float* __restrict__ tag, float* __restrict__ out) {
    int wid  = (blockIdx.x * 256 + threadIdx.x) >> 6;
    int lane = threadIdx.x & 63;
    if (wid >= B_ * T_) return;
    int b = wid / T_, t = wid % T_;
    const float* row = tag + (size_t)wid * S_;
    float v0 = row[lane], v1 = row[lane + 64];
    float m = fmaxf(v0, v1);
    #pragma unroll
    for (int off = 32; off; off >>= 1) m = fmaxf(m, __shfl_xor(m, off));
    float e = expf(v0 - m) + expf(v1 - m);
    #pragma unroll
    for (int off = 32; off; off >>= 1) e += __shfl_xor(e, off);
    float lse = m + logf(e);
    out[((size_t)b * S_ + lane)      * T_ + t] = v0 - lse;
    out[((size_t)b * S_ + lane + 64) * T_ + t] = v1 - lse;
}

// ---------------------------------------------------------------- launch
extern "C" void kernel_launch(void* const* d_in, const int* in_sizes, int n_in,
                              void* d_out, int out_size, void* d_ws, size_t ws_size,
                              hipStream_t stream) {
    const int*   char_ids = (const int*)d_in[0];
    const int*   word_ids = (const int*)d_in[1];
    const float* char_emb = (const float*)d_in[2];
    const float* word_emb = (const float*)d_in[3];
    const float* cnn_w    = (const float*)d_in[4];
    const float* cnn_b    = (const float*)d_in[5];
    const float* wih_f    = (const float*)d_in[6];
    const float* whh_f    = (const float*)d_in[7];
    const float* b_f      = (const float*)d_in[8];
    const float* wih_b    = (const float*)d_in[9];
    const float* whh_b    = (const float*)d_in[10];
    const float* b_b      = (const float*)d_in[11];
    const float* out_w    = (const float*)d_in[12];
    const float* out_b    = (const float*)d_in[13];
    float* out = (float*)d_out;
    char* ws   = (char*)d_ws;

    size_t o = 0;
    bf16* wihT_f = (bf16*)(ws + o); o += (size_t)128 * 1024 * 2;
    bf16* wihT_b = (bf16*)(ws + o); o += (size_t)128 * 1024 * 2;
    bf16* wp_f   = (bf16*)(ws + o); o += (size_t)256 * 1024 * 2;
    bf16* wp_b   = (bf16*)(ws + o); o += (size_t)256 * 1024 * 2;
    bf16* igq_f  = (bf16*)(ws + o); o += (size_t)S_ * B_ * 1024 * 2;
    bf16* igq_b  = (bf16*)(ws + o); o += (size_t)S_ * B_ * 1024 * 2;
    float* hf    = (float*)(ws + o); o += (size_t)S_ * B_ * 256 * 4;
    float* hb    = (float*)(ws + o); o += (size_t)S_ * B_ * 256 * 4;
    float* tag   = (float*)(ws + o); o += (size_t)B_ * T_ * S_ * 4;

    k_prep1<<<1536, 256, 0, stream>>>(whh_f, whh_b, wih_f, wih_b,
                                      wp_f, wp_b, wihT_f, wihT_b);
    k_input_proj<<<dim3(512, 2), 256, 0, stream>>>(word_ids, word_emb,
                                                   wihT_f, b_f, wihT_b, b_b, igq_f, igq_b);
    k_lstm_cnn<<<256, 1024, 0, stream>>>(igq_f, igq_b,
                                         (const uint4*)wp_f, (const uint4*)wp_b, hf, hb,
                                         char_ids, char_emb, cnn_w, cnn_b,
                                         out + (size_t)B_ * S_ * T_);
    k_tag_linear<<<B_ * S_ / 8, 512, 0, stream>>>(hf, hb, out_w, out_b, tag);
    k_log_softmax<<<(B_ * T_ + 3) / 4, 256, 0, stream>>>(tag, out);
}

// Round 16
// 372.771 us; speedup vs baseline: 1.3778x; 1.2098x over previous
//
#include <hip/hip_runtime.h>
#include <hip/hip_bf16.h>

#define B_  64
#define S_  128
#define WP_ 18
#define K_  3
#define E_  128
#define H_  256
#define L_  4
#define T_  50

typedef __hip_bfloat16 bf16;

__device__ __forceinline__ float b2f(bf16 x) { return __bfloat162float(x); }
__device__ __forceinline__ bf16  f2b(float x) { return __float2bfloat16(x); }

__device__ __forceinline__ float fast_sigmoid(float x) {
    return 1.f / (1.f + __expf(-x));
}
__device__ __forceinline__ float fast_tanh(float x) {
    float a = fminf(fmaxf(2.f * x, -30.f), 30.f);
    float e = __expf(a);
    return (e - 1.f) / (e + 1.f);
}
__device__ __forceinline__ unsigned int pack2(float lo, float hi) {
    bf16 l = f2b(lo), h = f2b(hi);
    unsigned short ls = *(unsigned short*)&l, hs = *(unsigned short*)&h;
    return ((unsigned int)hs << 16) | ls;
}

// v_dot2_f32_bf16: z += lo(w)*lo(h) + hi(w)*hi(h)
#define DOT2(z, w, h) asm("v_dot2_f32_bf16 %0, %1, %2, %0" : "+v"(z) : "v"(w), "v"(h))
// opaque pin: value becomes non-rematerializable
#define PIN4(V_) asm volatile("" : "+v"((V_).x), "+v"((V_).y), "+v"((V_).z), "+v"((V_).w))

// ---------------------------------------------------------------- prep: all weight repacks
// dst-linear u32 writes (coalesced), gather f32 reads.
// blocks [0,512): wp_f | [512,1024): wp_b | [1024,1280): wihT2_f | [1280,1536): wihT2_b
__global__ void k_prep(const float* __restrict__ whh_f, const float* __restrict__ whh_b,
                       const float* __restrict__ wih_f, const float* __restrict__ wih_b,
                       unsigned int* __restrict__ wp_f, unsigned int* __restrict__ wp_b,
                       unsigned int* __restrict__ wihT2_f, unsigned int* __restrict__ wihT2_b) {
    int blk = blockIdx.x, t = threadIdx.x;
    if (blk < 1024) {
        const float* src   = (blk < 512) ? whh_f : whh_b;
        unsigned int* dst  = (blk < 512) ? wp_f  : wp_b;
        int d = ((blk & 511) << 8) + t;            // u32 index over 1024*128
        int m = d >> 12, rem = d & 4095;
        int td = rem >> 2, epair = rem & 3, e = epair << 1;
        int i = td >> 2, p = td & 3, g = m >> 3, kk = m & 7;
        int col = (g << 8) + i;
        int k = (p << 6) + (kk << 3) + e;
        float2 sv = *(const float2*)(src + col * 256 + k);
        dst[d] = pack2(sv.x, sv.y);
    } else {
        int id = blk - 1024;
        const float* src  = (id < 256) ? wih_f   : wih_b;
        unsigned int* dst = (id < 256) ? wihT2_f : wihT2_b;
        int d = ((id & 255) << 8) + t;             // u32 index over 64*1024
        int kp = d >> 10, j = d & 1023;
        float2 sv = *(const float2*)(src + j * 128 + 2 * kp);
        dst[d] = pack2(sv.x, sv.y);                // wihT2[kp*1024 + j]
    }
}

// ---------------------------------------------------------------- input proj (DOT2, 16 rows/block)
__global__ void k_input_proj(const int* __restrict__ word_ids,
                             const float* __restrict__ word_emb,
                             const unsigned int* __restrict__ wihT2_f, const float* __restrict__ b_f,
                             const unsigned int* __restrict__ wihT2_b, const float* __restrict__ b_b,
                             bf16* __restrict__ igq_f, bf16* __restrict__ igq_b) {
    int dir = blockIdx.y;
    const unsigned int* wihT2 = dir ? wihT2_b : wihT2_f;
    const float* bb  = dir ? b_b   : b_f;
    bf16* igq        = dir ? igq_b : igq_f;
    __shared__ unsigned int x2[16][64];
    int t  = threadIdx.x;
    int r0 = blockIdx.x * 16;
    for (int u = t; u < 16 * 64; u += 256) {
        int rr = u >> 6, ep = u & 63;
        int r = r0 + rr;
        int s = r >> 6, b = r & 63;
        int wid = word_ids[b * S_ + s];
        float2 ev = *(const float2*)(word_emb + (size_t)wid * E_ + 2 * ep);
        x2[rr][ep] = pack2(ev.x, ev.y);
    }
    __syncthreads();
    int j = t;
    float acc[4][16];
    #pragma unroll
    for (int cj = 0; cj < 4; ++cj) {
        float bv = bb[j + cj * 256];
        #pragma unroll
        for (int rr = 0; rr < 16; ++rr) acc[cj][rr] = bv;
    }
    for (int kp = 0; kp < 64; ++kp) {
        unsigned int wv[4];
        #pragma unroll
        for (int cj = 0; cj < 4; ++cj) wv[cj] = wihT2[kp * 1024 + j + cj * 256];
        #pragma unroll
        for (int rr = 0; rr < 16; ++rr) {
            unsigned int xp = x2[rr][kp];
            #pragma unroll
            for (int cj = 0; cj < 4; ++cj) DOT2(acc[cj][rr], wv[cj], xp);
        }
    }
    #pragma unroll
    for (int rr = 0; rr < 16; ++rr) {
        uint2 w2;
        w2.x = pack2(acc[0][rr], acc[1][rr]);
        w2.y = pack2(acc[2][rr], acc[3][rr]);
        *(uint2*)(igq + (size_t)(r0 + rr) * 1024 + j * 4) = w2;   // coalesced 8B
    }
}

// ---------------------------------------------------------------- fused recurrence + char CNN
__global__ __launch_bounds__(1024, 4) void k_lstm_cnn(
        const bf16* __restrict__ igq_f, const bf16* __restrict__ igq_b,
        const uint4* __restrict__ wp_f, const uint4* __restrict__ wp_b,
        float* __restrict__ hf, float* __restrict__ hb,
        const int* __restrict__ char_ids, const float* __restrict__ char_emb,
        const float* __restrict__ cnn_w, const float* __restrict__ cnn_b,
        float* __restrict__ out_char) {
    __shared__ uint4 wlds[9216];                          // 144 KiB pool
    __shared__ __align__(16) unsigned int hpbuf[2][160];

    int t = threadIdx.x;

    if (blockIdx.x < 128) {
        // ======================= LSTM recurrence ==========================
        int b   = blockIdx.x & 63;
        int dir = blockIdx.x >> 6;
        const bf16* igq = dir ? igq_b : igq_f;
        const uint4* wp = dir ? wp_b  : wp_f;
        float* hs       = dir ? hb    : hf;

        int i = t >> 2, p = t & 3;

        for (int u = t; u < 9216; u += 1024) wlds[u] = wp[23 * 1024 + u];
        if (t < 320) ((unsigned int*)hpbuf)[t] = 0;
        float c_reg = 0.f;

        uint4 wreg[23];
        #pragma unroll
        for (int m = 0; m < 23; ++m) {
            wreg[m] = wp[m * 1024 + t];
            PIN4(wreg[m]);
        }
        __syncthreads();

        int cur = 0;
        int s0 = dir ? (S_ - 1) : 0;
        uint2 igu = *(const uint2*)&igq[((size_t)s0 * B_ + b) * 1024 + i * 4];

        for (int step = 0; step < S_; ++step) {
            int s = dir ? (S_ - 1 - step) : step;

            float z0 = 0.f, z1 = 0.f, z2 = 0.f, z3 = 0.f;
            if (p == 0) {
                z0 = __uint_as_float(igu.x << 16);
                z1 = __uint_as_float(igu.x & 0xffff0000u);
                z2 = __uint_as_float(igu.y << 16);
                z3 = __uint_as_float(igu.y & 0xffff0000u);
            }
            const char* hpc = (const char*)hpbuf[cur];
            #pragma unroll
            for (int kk = 0; kk < 8; ++kk) {
                uint4 hv = *(const uint4*)(hpc + p * 144 + kk * 16);
                {   uint4 wv = wreg[kk];
                    DOT2(z0, wv.x, hv.x); DOT2(z0, wv.y, hv.y);
                    DOT2(z0, wv.z, hv.z); DOT2(z0, wv.w, hv.w); }
                {   uint4 wv = wreg[8 + kk];
                    DOT2(z1, wv.x, hv.x); DOT2(z1, wv.y, hv.y);
                    DOT2(z1, wv.z, hv.z); DOT2(z1, wv.w, hv.w); }
                {   uint4 wv = (kk < 7) ? wreg[16 + kk] : wlds[t];
                    DOT2(z2, wv.x, hv.x); DOT2(z2, wv.y, hv.y);
                    DOT2(z2, wv.z, hv.z); DOT2(z2, wv.w, hv.w); }
                {   uint4 wv = wlds[(1 + kk) * 1024 + t];
                    DOT2(z3, wv.x, hv.x); DOT2(z3, wv.y, hv.y);
                    DOT2(z3, wv.z, hv.z); DOT2(z3, wv.w, hv.w); }
            }
            if (step + 1 < S_) {
                int sn = dir ? (S_ - 2 - step) : (step + 1);
                igu = *(const uint2*)&igq[((size_t)sn * B_ + b) * 1024 + i * 4];
            }
            z0 += __shfl_xor(z0, 1); z0 += __shfl_xor(z0, 2);
            z1 += __shfl_xor(z1, 1); z1 += __shfl_xor(z1, 2);
            z2 += __shfl_xor(z2, 1); z2 += __shfl_xor(z2, 2);
            z3 += __shfl_xor(z3, 1); z3 += __shfl_xor(z3, 2);
            if (p == 0) {
                float si = fast_sigmoid(z0);
                float sf = fast_sigmoid(z1);
                float tg = fast_tanh(z2);
                float so = fast_sigmoid(z3);
                c_reg = sf * c_reg + si * tg;
                float hn = so * fast_tanh(c_reg);
                hs[((size_t)s * B_ + b) * 256 + i] = hn;
                char* dstb = (char*)hpbuf[cur ^ 1] + (i >> 6) * 144 + ((i >> 1) & 31) * 4 + (i & 1) * 2;
                *(bf16*)dstb = f2b(hn);
            }
            __syncthreads();
            cur ^= 1;
        }
    } else {
        // ======================= char CNN on idle CUs ======================
        unsigned int* pool_u = (unsigned int*)wlds;
        float*        pool_f = (float*)wlds;
        int blkc = blockIdx.x - 128;

        for (int u = t; u < 4 * 192; u += 1024) {
            int c = u / 192, pe = u % 192;
            pool_u[c * 196 + pe] = pack2(cnn_w[c * 384 + 2 * pe], cnn_w[c * 384 + 2 * pe + 1]);
        }
        if (t < 4) pool_f[784 + t] = cnn_b[t];
        __syncthreads();

        int wv = t >> 6, lane = t & 63;
        unsigned int* cew = pool_u + 800 + wv * 1224;
        int pos = lane >> 2, c = lane & 3;

        #pragma unroll 1
        for (int j = 0; j < 4; ++j) {
            int word = (blkc * 16 + wv) * 4 + j;
            const int* ids = char_ids + word * WP_;
            for (int row = 0; row < WP_; ++row) {
                float2 ev = *(const float2*)(char_emb + (size_t)ids[row] * 128 + 2 * lane);
                cew[row * 68 + lane] = pack2(ev.x, ev.y);
            }
            float acc = 0.f;
            #pragma unroll
            for (int i = 0; i < K_; ++i) {
                const uint4* cr = (const uint4*)(cew + (pos + i) * 68);
                const uint4* wr = (const uint4*)(pool_u + c * 196 + i * 64);
                #pragma unroll
                for (int q = 0; q < 16; ++q) {
                    uint4 cv = cr[q], wq = wr[q];
                    DOT2(acc, wq.x, cv.x); DOT2(acc, wq.y, cv.y);
                    DOT2(acc, wq.z, cv.z); DOT2(acc, wq.w, cv.w);
                }
            }
            acc += pool_f[784 + c];
            #pragma unroll
            for (int off = 4; off < 64; off <<= 1) acc = fmaxf(acc, __shfl_xor(acc, off));
            if (lane < L_) out_char[(size_t)word * L_ + lane] = acc;
        }
    }
}

// ---------------------------------------------------------------- tag linear (LDS-resident out_w, DOT2)
// 8 words/block, 512 threads. ow padded 257 -> <=2-way conflicts (free).
__global__ void k_tag_linear(const float* __restrict__ hf, const float* __restrict__ hb,
                             const float* __restrict__ out_w, const float* __restrict__ out_b,
                             float* __restrict__ tag) {
    __shared__ unsigned int ow[50 * 257];      // 51400 B
    __shared__ unsigned int hv2[8][256];       // 32768 B
    int bs0 = blockIdx.x * 8;
    int t = threadIdx.x;                       // 0..511
    for (int u = t; u < 12800; u += 512) {
        int tt = u >> 8, kp = u & 255;
        float2 wv = *(const float2*)(out_w + tt * 512 + 2 * kp);
        ow[tt * 257 + kp] = pack2(wv.x, wv.y);
    }
    for (int u = t; u < 8 * 256; u += 512) {
        int w = u >> 8, q = u & 255;
        int bs = bs0 + w;
        int b = bs >> 7, s = bs & 127;
        const float* hsrc = (q < 128) ? hf : hb;
        float2 v = *(const float2*)(hsrc + ((size_t)s * B_ + b) * 256 + 2 * (q & 127));
        hv2[w][q] = pack2(v.x, v.y);
    }
    __syncthreads();
    int w = t >> 6, tt = t & 63;
    if (tt < T_) {
        int bs = bs0 + w;
        int b = bs >> 7, s = bs & 127;
        float acc = out_b[tt];
        const unsigned int* owr = &ow[tt * 257];
        const unsigned int* hvr = hv2[w];
        #pragma unroll 8
        for (int kp = 0; kp < 256; ++kp) DOT2(acc, owr[kp], hvr[kp]);
        tag[((size_t)b * T_ + tt) * S_ + s] = acc;
    }
}

// ---------------------------------------------------------------- log_softmax over S (axis=1)
__global__ void k_log_softmax(const float* __restrict__ tag, float* __restrict__ out) {
    int wid  = (blockIdx.x * 256 + threadIdx.x) >> 6;
    int lane = threadIdx.x & 63;
    if (wid >= B_ * T_) return;
    int b = wid / T_, t = wid % T_;
    const float* row = tag + (size_t)wid * S_;
    float v0 = row[lane], v1 = row[lane + 64];
    float m = fmaxf(v0, v1);
    #pragma unroll
    for (int off = 32; off; off >>= 1) m = fmaxf(m, __shfl_xor(m, off));
    float e = expf(v0 - m) + expf(v1 - m);
    #pragma unroll
    for (int off = 32; off; off >>= 1) e += __shfl_xor(e, off);
    float lse = m + logf(e);
    out[((size_t)b * S_ + lane)      * T_ + t] = v0 - lse;
    out[((size_t)b * S_ + lane + 64) * T_ + t] = v1 - lse;
}

// ---------------------------------------------------------------- launch
extern "C" void kernel_launch(void* const* d_in, const int* in_sizes, int n_in,
                              void* d_out, int out_size, void* d_ws, size_t ws_size,
                              hipStream_t stream) {
    const int*   char_ids = (const int*)d_in[0];
    const int*   word_ids = (const int*)d_in[1];
    const float* char_emb = (const float*)d_in[2];
    const float* word_emb = (const float*)d_in[3];
    const float* cnn_w    = (const float*)d_in[4];
    const float* cnn_b    = (const float*)d_in[5];
    const float* wih_f    = (const float*)d_in[6];
    const float* whh_f    = (const float*)d_in[7];
    const float* b_f      = (const float*)d_in[8];
    const float* wih_b    = (const float*)d_in[9];
    const float* whh_b    = (const float*)d_in[10];
    const float* b_b      = (const float*)d_in[11];
    const float* out_w    = (const float*)d_in[12];
    const float* out_b    = (const float*)d_in[13];
    float* out = (float*)d_out;
    char* ws   = (char*)d_ws;

    size_t o = 0;
    unsigned int* wihT2_f = (unsigned int*)(ws + o); o += (size_t)64 * 1024 * 4;
    unsigned int* wihT2_b = (unsigned int*)(ws + o); o += (size_t)64 * 1024 * 4;
    unsigned int* wp_f    = (unsigned int*)(ws + o); o += (size_t)1024 * 128 * 4;
    unsigned int* wp_b    = (unsigned int*)(ws + o); o += (size_t)1024 * 128 * 4;
    bf16* igq_f  = (bf16*)(ws + o); o += (size_t)S_ * B_ * 1024 * 2;
    bf16* igq_b  = (bf16*)(ws + o); o += (size_t)S_ * B_ * 1024 * 2;
    float* hf    = (float*)(ws + o); o += (size_t)S_ * B_ * 256 * 4;
    float* hb    = (float*)(ws + o); o += (size_t)S_ * B_ * 256 * 4;
    float* tag   = (float*)(ws + o); o += (size_t)B_ * T_ * S_ * 4;

    k_prep<<<1536, 256, 0, stream>>>(whh_f, whh_b, wih_f, wih_b,
                                     wp_f, wp_b, wihT2_f, wihT2_b);
    k_input_proj<<<dim3(512, 2), 256, 0, stream>>>(word_ids, word_emb,
                                                   wihT2_f, b_f, wihT2_b, b_b, igq_f, igq_b);
    k_lstm_cnn<<<256, 1024, 0, stream>>>(igq_f, igq_b,
                                         (const uint4*)wp_f, (const uint4*)wp_b, hf, hb,
                                         char_ids, char_emb, cnn_w, cnn_b,
                                         out + (size_t)B_ * S_ * T_);
    k_tag_linear<<<B_ * S_ / 8, 512, 0, stream>>>(hf, hb, out_w, out_b, tag);
    k_log_softmax<<<(B_ * T_ + 3) / 4, 256, 0, stream>>>(tag, out);
}